// Round 2
// baseline (26414.267 us; speedup 1.0000x reference)
//
#include <hip/hip_runtime.h>
#include <math.h>

constexpr int BATCH = 256;
constexpr int EQ_   = 192;
constexpr int EC_   = 240;
constexpr int EPG   = 432;   // edges per pair
constexpr int NPG   = 216;   // nodes per pair

__device__ __forceinline__ void lse_merge(float& m, float& s, float om, float os) {
  const float nm = fmaxf(m, om);
  s = s * __expf(m - nm) + os * __expf(om - nm);
  m = nm;
}
__device__ __forceinline__ void lse_online(float& m, float& s, float tt) {
  if (tt > m) { s = s * __expf(m - tt) + 1.f; m = tt; }
  else        { s += __expf(tt - m); }
}

// ---------------------------------------------------------------------------
// Fused 2-layer MLP:  Y = relu(gather(X) @ W1 + b1) @ W2 + b2
// IN_MODE: 0 plain X  1 [h[from],h[to],comb]  2 [h[to],h[from],comb]
//          3 [h,agg_f,agg_b]  4 [e, inter(or 0 if ZERO2)]
//          5 q-side rows of e (zero-padded to 256)  6 c-side rows of e
// OUT_MODE: 0 write  1 add  2 atomicAdd at (SIDX[row]-nodeBase)
// SINGLE: 1 -> single layer (X@W1+b1, no relu)
// ---------------------------------------------------------------------------
template<int K1, int HID, int NOUT, int IN_MODE, int OUT_MODE, int SINGLE, int ZERO2>
__global__ __launch_bounds__(256)
void fused_mlp(const float* __restrict__ X,
               const float* __restrict__ P1, const float* __restrict__ P2,
               const float* __restrict__ P3,
               const int* __restrict__ IA, const int* __restrict__ IB,
               const float* __restrict__ W1, const float* __restrict__ B1,
               const float* __restrict__ W2, const float* __restrict__ B2,
               float* __restrict__ Y, const int* __restrict__ SIDX,
               int maskLen, int nodeBase)
{
  constexpr int RT = 32, BK = 32;
  constexpr int J1 = HID / 32;
  constexpr int J2 = NOUT / 32;
  constexpr int BMAX = (HID > NOUT ? HID : NOUT);
  __shared__ float sA[RT * 33];
  __shared__ float sB[BK * BMAX];
  __shared__ float sH[SINGLE ? 1 : RT * (HID + 1)];

  const int t  = threadIdx.x;
  const int tx = t & 31, ty = t >> 5;
  const int rowBase = blockIdx.x * RT;

  float acc[4][J1];
  #pragma unroll
  for (int i = 0; i < 4; ++i)
    #pragma unroll
    for (int j = 0; j < J1; ++j) acc[i][j] = 0.f;

  for (int kb = 0; kb < K1; kb += BK) {
    for (int l = t; l < RT * BK; l += 256) {
      const int r = l >> 5, k = l & 31;
      const int gr = rowBase + r, gk = kb + k;
      float v;
      if constexpr (IN_MODE == 0) {
        v = X[(size_t)gr * K1 + gk];
      } else if constexpr (IN_MODE == 1) {
        if (gk < 64)       v = P1[(size_t)(IA[gr] - nodeBase) * 64 + gk];
        else if (gk < 128) v = P1[(size_t)(IB[gr] - nodeBase) * 64 + (gk - 64)];
        else               v = P2[(size_t)gr * 128 + (gk - 128)];
      } else if constexpr (IN_MODE == 2) {
        if (gk < 64)       v = P1[(size_t)(IB[gr] - nodeBase) * 64 + gk];
        else if (gk < 128) v = P1[(size_t)(IA[gr] - nodeBase) * 64 + (gk - 64)];
        else               v = P2[(size_t)gr * 128 + (gk - 128)];
      } else if constexpr (IN_MODE == 3) {
        if (gk < 64)       v = P1[(size_t)gr * 64 + gk];
        else if (gk < 192) v = P2[(size_t)gr * 128 + (gk - 64)];
        else               v = P3[(size_t)gr * 128 + (gk - 192)];
      } else if constexpr (IN_MODE == 4) {
        if (gk < 128) v = P1[(size_t)gr * 128 + gk];
        else          v = ZERO2 ? 0.f : P2[(size_t)gr * 128 + (gk - 128)];
      } else {
        const int bb = gr >> 8, m = gr & 255;
        constexpr int off = (IN_MODE == 5) ? 0 : EQ_;
        constexpr int len = (IN_MODE == 5) ? EQ_ : EC_;
        v = (m < len) ? P1[((size_t)bb * EPG + off + m) * 128 + gk] : 0.f;
      }
      sA[r * 33 + k] = v;
    }
    for (int l = t * 4; l < BK * HID; l += 1024) {
      *(float4*)&sB[l] = *(const float4*)&W1[(size_t)(kb + l / HID) * HID + (l % HID)];
    }
    __syncthreads();
    #pragma unroll
    for (int k = 0; k < BK; ++k) {
      const float a0 = sA[(ty*4+0)*33+k], a1 = sA[(ty*4+1)*33+k],
                  a2 = sA[(ty*4+2)*33+k], a3 = sA[(ty*4+3)*33+k];
      #pragma unroll
      for (int j = 0; j < J1; ++j) {
        const float bb = sB[k * HID + tx + 32*j];
        acc[0][j] += a0 * bb; acc[1][j] += a1 * bb;
        acc[2][j] += a2 * bb; acc[3][j] += a3 * bb;
      }
    }
    __syncthreads();
  }

  if constexpr (SINGLE) {
    #pragma unroll
    for (int j = 0; j < J1; ++j) {
      const int col = tx + 32*j;
      const float bias = B1[col];
      #pragma unroll
      for (int i = 0; i < 4; ++i) {
        const int gr = rowBase + ty*4 + i;
        Y[(size_t)gr * HID + col] = acc[i][j] + bias;
      }
    }
  } else {
    #pragma unroll
    for (int j = 0; j < J1; ++j) {
      const int col = tx + 32*j;
      const float bias = B1[col];
      #pragma unroll
      for (int i = 0; i < 4; ++i) {
        float y = acc[i][j] + bias;
        sH[(ty*4+i) * (HID+1) + col] = y > 0.f ? y : 0.f;
      }
    }
    __syncthreads();

    float acc2[4][J2];
    #pragma unroll
    for (int i = 0; i < 4; ++i)
      #pragma unroll
      for (int j = 0; j < J2; ++j) acc2[i][j] = 0.f;

    for (int kb = 0; kb < HID; kb += BK) {
      for (int l = t * 4; l < BK * NOUT; l += 1024) {
        *(float4*)&sB[l] = *(const float4*)&W2[(size_t)(kb + l / NOUT) * NOUT + (l % NOUT)];
      }
      __syncthreads();
      #pragma unroll
      for (int k = 0; k < BK; ++k) {
        const float a0 = sH[(ty*4+0)*(HID+1) + kb + k],
                    a1 = sH[(ty*4+1)*(HID+1) + kb + k],
                    a2 = sH[(ty*4+2)*(HID+1) + kb + k],
                    a3 = sH[(ty*4+3)*(HID+1) + kb + k];
        #pragma unroll
        for (int j = 0; j < J2; ++j) {
          const float bb = sB[k * NOUT + tx + 32*j];
          acc2[0][j] += a0 * bb; acc2[1][j] += a1 * bb;
          acc2[2][j] += a2 * bb; acc2[3][j] += a3 * bb;
        }
      }
      __syncthreads();
    }
    #pragma unroll
    for (int j = 0; j < J2; ++j) {
      const int col = tx + 32*j;
      const float bias = B2[col];
      #pragma unroll
      for (int i = 0; i < 4; ++i) {
        const int gr = rowBase + ty*4 + i;
        float y = acc2[i][j] + bias;
        if (maskLen >= 0 && (gr & 255) >= maskLen) y = 0.f;
        if constexpr (OUT_MODE == 0)      Y[(size_t)gr * NOUT + col] = y;
        else if constexpr (OUT_MODE == 1) Y[(size_t)gr * NOUT + col] += y;
        else atomicAdd(&Y[(size_t)(SIDX[gr] - nodeBase) * 128 + col], y);
      }
    }
  }
}

// ---------------------------------------------------------------------------
// S[b] = scale * fq[b] @ fc[b]^T   (fq,fc: (C,256,64); S: (C,256,256))
// ---------------------------------------------------------------------------
__global__ __launch_bounds__(256)
void gemm_nt_scale(const float* __restrict__ A, const float* __restrict__ Bm,
                   float* __restrict__ C, float scale)
{
  const int b = blockIdx.z, qt = blockIdx.x, ct = blockIdx.y;
  __shared__ float sA[64 * 68];
  __shared__ float sB[64 * 68];
  const int t = threadIdx.x;
  const int tx = t & 15, ty = t >> 4;
  const float* Ab = A  + (size_t)b * 16384 + (size_t)qt * 4096;
  const float* Bb = Bm + (size_t)b * 16384 + (size_t)ct * 4096;
  for (int l = t * 4; l < 64 * 64; l += 1024) {
    const int r = l >> 6, d = l & 63;
    *(float4*)&sA[r*68 + d] = *(const float4*)&Ab[r*64 + d];
    *(float4*)&sB[r*68 + d] = *(const float4*)&Bb[r*64 + d];
  }
  __syncthreads();
  float acc[4][4] = {};
  #pragma unroll
  for (int d = 0; d < 64; ++d) {
    float a[4], bb[4];
    #pragma unroll
    for (int i = 0; i < 4; ++i) a[i]  = sA[(ty*4+i)*68 + d];
    #pragma unroll
    for (int j = 0; j < 4; ++j) bb[j] = sB[(tx+16*j)*68 + d];
    #pragma unroll
    for (int i = 0; i < 4; ++i)
      #pragma unroll
      for (int j = 0; j < 4; ++j) acc[i][j] += a[i] * bb[j];
  }
  float* Cb = C + (size_t)b * 65536 + (size_t)(qt*64) * 256 + ct*64;
  #pragma unroll
  for (int i = 0; i < 4; ++i)
    #pragma unroll
    for (int j = 0; j < 4; ++j)
      Cb[(ty*4+i)*256 + tx + 16*j] = acc[i][j] * scale;
}

// ---------------------------------------------------------------------------
// Y rows r<maskRows at ((b*RPB + YOFF + r)*128) = op(P[b]) @ V,
// V gathered from e: row vr -> e[(b*EPG + VOFF + vr)*128], zero if vr>=VLEN.
// TRANSA=0: C[q,d]=sum_c P[q,c]V[c,d]; TRANSA=1: C[c,d]=sum_q P[q,c]V[q,d]
// ---------------------------------------------------------------------------
template<int TRANSA>
__global__ __launch_bounds__(256)
void gemm_plan(const float* __restrict__ P, const float* __restrict__ E,
               float* __restrict__ Y, int RPB, int YOFF, int VOFF, int VLEN,
               int maskRows)
{
  const int b = blockIdx.y, rt = blockIdx.x;
  __shared__ float sA[64 * 33];
  __shared__ float sB[32 * 128];
  const int t = threadIdx.x;
  const int tx = t & 15, ty = t >> 4;
  const float* Pb = P + (size_t)b * 65536;
  float acc[4][8] = {};
  for (int kb = 0; kb < 256; kb += 32) {
    if constexpr (TRANSA == 0) {
      for (int l = t; l < 64 * 32; l += 256) {
        const int r = l >> 5, k = l & 31;
        sA[r*33 + k] = Pb[(size_t)(rt*64 + r) * 256 + kb + k];
      }
    } else {
      for (int l = t; l < 64 * 32; l += 256) {
        const int r = l & 63, k = l >> 6;
        sA[r*33 + k] = Pb[(size_t)(kb + k) * 256 + rt*64 + r];
      }
    }
    for (int l = t * 4; l < 32 * 128; l += 1024) {
      const int vr = kb + (l >> 7), d = l & 127;
      float4 val = {0.f, 0.f, 0.f, 0.f};
      if (vr < VLEN) val = *(const float4*)&E[((size_t)b * EPG + VOFF + vr) * 128 + d];
      *(float4*)&sB[l] = val;
    }
    __syncthreads();
    #pragma unroll
    for (int k = 0; k < 32; ++k) {
      float a[4], bb[8];
      #pragma unroll
      for (int i = 0; i < 4; ++i) a[i]  = sA[(ty*4+i)*33 + k];
      #pragma unroll
      for (int j = 0; j < 8; ++j) bb[j] = sB[k*128 + tx + 16*j];
      #pragma unroll
      for (int i = 0; i < 4; ++i)
        #pragma unroll
        for (int j = 0; j < 8; ++j) acc[i][j] += a[i] * bb[j];
    }
    __syncthreads();
  }
  #pragma unroll
  for (int i = 0; i < 4; ++i) {
    const int r = rt*64 + ty*4 + i;
    if (r >= maskRows) continue;
    float* yr = Y + ((size_t)b * RPB + YOFF + r) * 128;
    #pragma unroll
    for (int j = 0; j < 8; ++j) yr[tx + 16*j] = acc[i][j];
  }
}

// ---------------------------------------------------------------------------
// sinkhorn potential steps (per chunk of C pairs)
// ---------------------------------------------------------------------------
__global__ __launch_bounds__(256)
void sink_rowstep(const float* __restrict__ S, const float* __restrict__ v,
                  float* __restrict__ u)
{
  const int row  = blockIdx.x * 4 + (threadIdx.x >> 6);
  const int lane = threadIdx.x & 63;
  const int b = row >> 8;
  const float* Sr = S + (size_t)row * 256;
  const float* vb = v + b * 256;
  float m = -1e30f, s = 0.f;
  #pragma unroll
  for (int j = 0; j < 4; ++j) {
    const int c = lane + 64 * j;
    lse_online(m, s, Sr[c] + vb[c]);
  }
  #pragma unroll
  for (int off = 32; off; off >>= 1) {
    const float om = __shfl_xor(m, off);
    const float os = __shfl_xor(s, off);
    lse_merge(m, s, om, os);
  }
  if (lane == 0) u[row] = -(m + __logf(s));
}

__global__ __launch_bounds__(256)
void sink_colstep(const float* __restrict__ S, const float* __restrict__ u,
                  float* __restrict__ v)
{
  const int b = blockIdx.y;
  const int c = blockIdx.x * 64 + (threadIdx.x & 63);
  const int rg = threadIdx.x >> 6;
  const float* Sb = S + ((size_t)b << 16);
  const float* ub = u + b * 256;
  float m = -1e30f, s = 0.f;
  for (int r = rg * 64; r < rg * 64 + 64; ++r)
    lse_online(m, s, Sb[(size_t)r * 256 + c] + ub[r]);
  __shared__ float sm[256], ss[256];
  sm[threadIdx.x] = m; ss[threadIdx.x] = s;
  __syncthreads();
  if (rg == 0) {
    #pragma unroll
    for (int k = 1; k < 4; ++k)
      lse_merge(m, s, sm[threadIdx.x + 64*k], ss[threadIdx.x + 64*k]);
    v[b * 256 + c] = -(m + __logf(s));
  }
}

__global__ __launch_bounds__(256)
void planify(float* __restrict__ S, const float* __restrict__ u,
             const float* __restrict__ v)
{
  const int i = blockIdx.x * 256 + threadIdx.x;   // over C*16384 float4
  const int row = i >> 6;
  const int c4 = (i & 63) * 4;
  const int b = row >> 8;
  const float uu = u[row];
  const float* vb = v + b * 256;
  float4 sv = *(float4*)&S[(size_t)row * 256 + c4];
  sv.x = __expf(sv.x + uu + vb[c4+0]);
  sv.y = __expf(sv.y + uu + vb[c4+1]);
  sv.z = __expf(sv.z + uu + vb[c4+2]);
  sv.w = __expf(sv.w + uu + vb[c4+3]);
  *(float4*)&S[(size_t)row * 256 + c4] = sv;
}

// ---------------------------------------------------------------------------
// score[b] = -sum_{m<256,d} | (m<EQ ? e_q[m,d] : 0) - pc[m,d] |
// ---------------------------------------------------------------------------
__global__ __launch_bounds__(256)
void escore_kernel(const float* __restrict__ e, const float* __restrict__ pc,
                   float* __restrict__ out)
{
  const int b = blockIdx.x, t = threadIdx.x;
  float acc = 0.f;
  for (int i4 = t; i4 < 8192; i4 += 256) {
    const int flat = i4 * 4;
    const int m = flat >> 7, d = flat & 127;
    float4 p = *(const float4*)&pc[((size_t)b * 256 + m) * 128 + d];
    float4 q = {0.f, 0.f, 0.f, 0.f};
    if (m < EQ_) q = *(const float4*)&e[((size_t)b * EPG + m) * 128 + d];
    acc += fabsf(q.x - p.x) + fabsf(q.y - p.y) + fabsf(q.z - p.z) + fabsf(q.w - p.w);
  }
  __shared__ float red[256];
  red[t] = acc; __syncthreads();
  for (int s2 = 128; s2 > 0; s2 >>= 1) { if (t < s2) red[t] += red[t + s2]; __syncthreads(); }
  if (t == 0) out[b] = -red[0];
}

// ---------------------------------------------------------------------------
extern "C" void kernel_launch(void* const* d_in, const int* in_sizes, int n_in,
                              void* d_out, int out_size, void* d_ws, size_t ws_size,
                              hipStream_t stream)
{
  const float* node_features = (const float*)d_in[0];
  const float* edge_features = (const float*)d_in[1];
  const int*   from_idx      = (const int*)d_in[2];
  const int*   to_idx        = (const int*)d_in[3];
  const float* enc_node_W = (const float*)d_in[4];
  const float* enc_node_b = (const float*)d_in[5];
  const float* enc_edge_W = (const float*)d_in[6];
  const float* enc_edge_b = (const float*)d_in[7];
  const float* msg_W1 = (const float*)d_in[8];
  const float* msg_b1 = (const float*)d_in[9];
  const float* msg_W2 = (const float*)d_in[10];
  const float* msg_b2 = (const float*)d_in[11];
  const float* upd_W1 = (const float*)d_in[12];
  const float* upd_b1 = (const float*)d_in[13];
  const float* upd_W2 = (const float*)d_in[14];
  const float* upd_b2 = (const float*)d_in[15];
  const float* int_W1 = (const float*)d_in[16];
  const float* int_b1 = (const float*)d_in[17];
  const float* int_W2 = (const float*)d_in[18];
  const float* int_b2 = (const float*)d_in[19];
  const float* sink_W1 = (const float*)d_in[20];
  const float* sink_b1 = (const float*)d_in[21];
  const float* sink_W2 = (const float*)d_in[22];
  const float* sink_b2 = (const float*)d_in[23];
  float* out = (float*)d_out;

  // chunk size: largest power-of-two C (>=4) whose workspace fits ws_size.
  // per-pair floats: h 13824 + e 55296 + ci 55296 + agg 55296 + S 65536 + u/v 512
  int C = 256;
  while (C > 4 && (size_t)C * 983040ull > ws_size) C >>= 1;
  const int nch = BATCH / C;

  float* wsf = (float*)d_ws;
  const size_t szH = (size_t)C * NPG * 64;
  const size_t szE = (size_t)C * EPG * 128;
  const size_t szS = (size_t)C * 65536;
  float* h  = wsf;
  float* e  = h  + szH;
  float* ci = e  + szE;            // comb / inter / pc (aliased, disjoint lifetimes)
  float* ag = ci + szE;            // aggF | aggB ; later fq | fc
  float* S  = ag + szE;
  float* u  = S  + szS;
  float* v  = u  + (size_t)C * 256;

  float* aggF = ag;
  float* aggB = ag + (size_t)C * NPG * 128;
  float* fq   = ag;
  float* fc   = ag + (size_t)C * 16384;

  const int NNc = C * NPG, NEc = C * EPG;

  for (int ch = 0; ch < nch; ++ch) {
    const float* nf  = node_features + (size_t)ch * NNc * 32;
    const float* ef  = edge_features + (size_t)ch * NEc * 32;
    const int* fidx  = from_idx + (size_t)ch * NEc;
    const int* tidx  = to_idx   + (size_t)ch * NEc;
    const int nodeBase = ch * NNc;

    for (int ts = 0; ts < 2; ++ts) {
      // encoders (recomputed each time step; resets h, e)
      fused_mlp<32,64,64,0,0,1,0><<<NNc/32, 256, 0, stream>>>(
          nf, nullptr, nullptr, nullptr, nullptr, nullptr,
          enc_node_W, enc_node_b, nullptr, nullptr, h, nullptr, -1, 0);
      fused_mlp<32,128,128,0,0,1,0><<<NEc/32, 256, 0, stream>>>(
          ef, nullptr, nullptr, nullptr, nullptr, nullptr,
          enc_edge_W, enc_edge_b, nullptr, nullptr, e, nullptr, -1, 0);

      for (int p = 0; p < 3; ++p) {
        // comb = MLP([e, inter]); inter==0 for all of ts0 and first step of ts1
        if (ts == 0 || p == 0)
          fused_mlp<256,256,128,4,0,0,1><<<NEc/32, 256, 0, stream>>>(
              nullptr, e, nullptr, nullptr, nullptr, nullptr,
              int_W1, int_b1, int_W2, int_b2, ci, nullptr, -1, 0);
        else
          fused_mlp<256,256,128,4,0,0,0><<<NEc/32, 256, 0, stream>>>(
              nullptr, e, ci, nullptr, nullptr, nullptr,
              int_W1, int_b1, int_W2, int_b2, ci, nullptr, -1, 0);
        // bidirectional messages scatter-added to node aggregates
        hipMemsetAsync(ag, 0, szE * 4, stream);
        fused_mlp<256,256,128,1,2,0,0><<<NEc/32, 256, 0, stream>>>(
            nullptr, h, ci, nullptr, fidx, tidx,
            msg_W1, msg_b1, msg_W2, msg_b2, aggF, tidx, -1, nodeBase);
        fused_mlp<256,256,128,2,2,0,0><<<NEc/32, 256, 0, stream>>>(
            nullptr, h, ci, nullptr, fidx, tidx,
            msg_W1, msg_b1, msg_W2, msg_b2, aggB, fidx, -1, nodeBase);
        // node update (in place)
        fused_mlp<320,128,64,3,0,0,0><<<NNc/32, 256, 0, stream>>>(
            nullptr, h, aggF, aggB, nullptr, nullptr,
            upd_W1, upd_b1, upd_W2, upd_b2, h, nullptr, -1, 0);
        // e = mf2 + mb2 with updated h
        fused_mlp<256,256,128,1,0,0,0><<<NEc/32, 256, 0, stream>>>(
            nullptr, h, ci, nullptr, fidx, tidx,
            msg_W1, msg_b1, msg_W2, msg_b2, e, nullptr, -1, nodeBase);
        fused_mlp<256,256,128,2,1,0,0><<<NEc/32, 256, 0, stream>>>(
            nullptr, h, ci, nullptr, fidx, tidx,
            msg_W1, msg_b1, msg_W2, msg_b2, e, nullptr, -1, nodeBase);
        // interaction features from last time step's transport plan
        if (ts == 1 && p < 2) {
          gemm_plan<0><<<dim3(4, C), 256, 0, stream>>>(
              S, e, ci, EPG, 0,   EQ_, EC_, EQ_);   // q_int = plan @ cs
          gemm_plan<1><<<dim3(4, C), 256, 0, stream>>>(
              S, e, ci, EPG, EQ_, 0,   EQ_, EC_);   // c_int = plan^T @ qs
        }
      }
      // sinkhorn features (padded gather folded in; masked rows -> 0)
      fused_mlp<128,64,64,5,0,0,0><<<C*8, 256, 0, stream>>>(
          nullptr, e, nullptr, nullptr, nullptr, nullptr,
          sink_W1, sink_b1, sink_W2, sink_b2, fq, nullptr, EQ_, 0);
      fused_mlp<128,64,64,6,0,0,0><<<C*8, 256, 0, stream>>>(
          nullptr, e, nullptr, nullptr, nullptr, nullptr,
          sink_W1, sink_b1, sink_W2, sink_b2, fc, nullptr, EC_, 0);
      gemm_nt_scale<<<dim3(4,4,C), 256, 0, stream>>>(fq, fc, S, 10.0f); // 1/TEMP
      hipMemsetAsync(v, 0, (size_t)C * 256 * 4, stream);
      for (int it = 0; it < 10; ++it) {
        sink_rowstep<<<C*64, 256, 0, stream>>>(S, v, u);
        sink_colstep<<<dim3(4, C), 256, 0, stream>>>(S, u, v);
      }
      planify<<<C*64, 256, 0, stream>>>(S, u, v);   // S := plan
    }

    // final score: pc = plan @ cs (dense 256 rows), then -||qs - pc||_1
    gemm_plan<0><<<dim3(4, C), 256, 0, stream>>>(S, e, ci, 256, 0, EQ_, EC_, 256);
    escore_kernel<<<C, 256, 0, stream>>>(e, ci, out + ch * C);
  }
}

// Round 3
// 5592.263 us; speedup vs baseline: 4.7234x; 4.7234x over previous
//
#include <hip/hip_runtime.h>
#include <math.h>

constexpr int BATCH = 256;
constexpr int EQ_   = 192;
constexpr int EC_   = 240;
constexpr int EPG   = 432;   // edges per pair
constexpr int NPG   = 216;   // nodes per pair
constexpr int NN    = BATCH * NPG;   // 55296
constexpr int NE    = BATCH * EPG;   // 110592

typedef __attribute__((ext_vector_type(8))) short short8;
typedef __attribute__((ext_vector_type(4))) float floatx4;
typedef unsigned short u16;

__device__ __forceinline__ u16 f2bf(float x) {
  union { float f; unsigned u; } c; c.f = x;
  const unsigned r = (c.u + 0x7FFFu + ((c.u >> 16) & 1u)) >> 16;
  return (u16)r;
}
__device__ __forceinline__ short8 cvt8(const float* __restrict__ p) {
  const float4 a = *(const float4*)p;
  const float4 b = *(const float4*)(p + 4);
  short8 o;
  o[0]=(short)f2bf(a.x); o[1]=(short)f2bf(a.y); o[2]=(short)f2bf(a.z); o[3]=(short)f2bf(a.w);
  o[4]=(short)f2bf(b.x); o[5]=(short)f2bf(b.y); o[6]=(short)f2bf(b.z); o[7]=(short)f2bf(b.w);
  return o;
}

__device__ __forceinline__ void lse_merge(float& m, float& s, float om, float os) {
  const float nm = fmaxf(m, om);
  s = s * __expf(m - nm) + os * __expf(om - nm);
  m = nm;
}
__device__ __forceinline__ void lse_online(float& m, float& s, float tt) {
  if (tt > m) { s = s * __expf(m - tt) + 1.f; m = tt; }
  else        { s += __expf(tt - m); }
}

// ---------------------------------------------------------------------------
// weight transpose + f32->bf16:  out[n*K+k] = bf16(W[k*N+n])
// ---------------------------------------------------------------------------
__global__ __launch_bounds__(256)
void wconv(const float* __restrict__ W, u16* __restrict__ out, int K, int N)
{
  const int i = blockIdx.x * 256 + threadIdx.x;
  if (i < K * N) {
    const int n = i / K, k = i - n * K;
    out[i] = f2bf(W[(size_t)k * N + n]);
  }
}

// ---------------------------------------------------------------------------
// Generic MFMA fused 2-layer MLP over 64-row tiles.
// IN_MODE: 1 [h[from],h[to],comb_bf16]  3 [h,aggF,aggB]  4 [e, inter(or 0)]
// DUAL: run twice with first-two-64-col-blocks swapped (k^64), sum outputs.
// OUT_BF16: write bf16 (else f32).
// ---------------------------------------------------------------------------
template<int K1, int HID, int NOUT, int IN_MODE, int DUAL, int OUT_BF16>
__global__ __launch_bounds__(256)
void mlp_mfma(const float* __restrict__ X, const float* __restrict__ P2,
              const float* __restrict__ P3, const u16* __restrict__ CB,
              const int* __restrict__ IA, const int* __restrict__ IB,
              const u16* __restrict__ W1t, const float* __restrict__ B1,
              const u16* __restrict__ W2t, const float* __restrict__ B2,
              float* __restrict__ Yf, u16* __restrict__ Yb)
{
  constexpr int KCH = K1 / 8;
  constexpr int NT1 = HID / 64;     // n-tiles per wave, layer1
  constexpr int NT2 = NOUT / 64;    // n-tiles per wave, layer2 (>=1)
  __shared__ u16 sA[64 * K1];
  __shared__ u16 sH[64 * (HID + 8)];

  const int tid = threadIdx.x;
  const int rowBase = blockIdx.x * 64;

  // ---- stage A panel (gather + cvt), XOR-swizzled rows ----
  for (int ch = tid; ch < 64 * KCH; ch += 256) {
    const int r = ch / KCH, kc = ch - r * KCH;
    const int gr = rowBase + r, k0 = kc * 8;
    short8 pk;
    if constexpr (IN_MODE == 4) {
      if (k0 < 128)      pk = cvt8(&X[(size_t)gr * 128 + k0]);
      else if (P2)       pk = cvt8(&P2[(size_t)gr * 128 + (k0 - 128)]);
      else { pk = short8{0,0,0,0,0,0,0,0}; }
    } else if constexpr (IN_MODE == 1) {
      if (k0 < 64)       pk = cvt8(&X[(size_t)IA[gr] * 64 + k0]);
      else if (k0 < 128) pk = cvt8(&X[(size_t)IB[gr] * 64 + (k0 - 64)]);
      else               pk = *(const short8*)&CB[(size_t)gr * 128 + (k0 - 128)];
    } else { // 3
      if (k0 < 64)       pk = cvt8(&X[(size_t)gr * 64 + k0]);
      else if (k0 < 192) pk = cvt8(&P2[(size_t)gr * 128 + (k0 - 64)]);
      else               pk = cvt8(&P3[(size_t)gr * 128 + (k0 - 192)]);
    }
    const int byte = ((r * K1 + k0) * 2) ^ ((r & 7) << 4);
    *(short8*)((char*)sA + byte) = pk;
  }
  __syncthreads();

  const int wid = tid >> 6, lane = tid & 63;
  const int l15 = lane & 15, lg = lane >> 4;

  floatx4 accO[4][NT2];
  #pragma unroll
  for (int m = 0; m < 4; ++m)
    #pragma unroll
    for (int n = 0; n < NT2; ++n) accO[m][n] = floatx4{0.f,0.f,0.f,0.f};

  for (int dir = 0; dir < 1 + DUAL; ++dir) {
    // ---- layer 1 ----
    floatx4 acc1[4][NT1];
    #pragma unroll
    for (int m = 0; m < 4; ++m)
      #pragma unroll
      for (int n = 0; n < NT1; ++n) acc1[m][n] = floatx4{0.f,0.f,0.f,0.f};

    for (int kk = 0; kk < K1 / 32; ++kk) {
      short8 bf[NT1];
      #pragma unroll
      for (int n = 0; n < NT1; ++n) {
        const int col = wid * (HID / 4) + n * 16 + l15;
        bf[n] = *(const short8*)&W1t[(size_t)col * K1 + kk * 32 + lg * 8];
      }
      #pragma unroll
      for (int m = 0; m < 4; ++m) {
        const int r = m * 16 + l15;
        int k0 = kk * 32 + lg * 8;
        if constexpr (DUAL) { if (dir && k0 < 128) k0 ^= 64; }
        const int byte = ((r * K1 + k0) * 2) ^ ((r & 7) << 4);
        const short8 af = *(const short8*)((char*)sA + byte);
        #pragma unroll
        for (int n = 0; n < NT1; ++n)
          acc1[m][n] = __builtin_amdgcn_mfma_f32_16x16x32_bf16(af, bf[n], acc1[m][n], 0, 0, 0);
      }
    }
    __syncthreads();   // all waves done reading sH from previous pass
    // ---- hidden: bias + relu -> bf16 LDS ----
    #pragma unroll
    for (int n = 0; n < NT1; ++n) {
      const int col = wid * (HID / 4) + n * 16 + l15;
      const float b1 = B1[col];
      #pragma unroll
      for (int m = 0; m < 4; ++m)
        #pragma unroll
        for (int r = 0; r < 4; ++r) {
          const int row = m * 16 + lg * 4 + r;
          float y = acc1[m][n][r] + b1;
          sH[row * (HID + 8) + col] = f2bf(y > 0.f ? y : 0.f);
        }
    }
    __syncthreads();
    // ---- layer 2 ----
    for (int kk = 0; kk < HID / 32; ++kk) {
      short8 bf2[NT2];
      #pragma unroll
      for (int n = 0; n < NT2; ++n) {
        const int col = wid * (NOUT / 4) + n * 16 + l15;
        bf2[n] = *(const short8*)&W2t[(size_t)col * HID + kk * 32 + lg * 8];
      }
      #pragma unroll
      for (int m = 0; m < 4; ++m) {
        const int r = m * 16 + l15;
        const short8 af = *(const short8*)&sH[r * (HID + 8) + kk * 32 + lg * 8];
        #pragma unroll
        for (int n = 0; n < NT2; ++n)
          accO[m][n] = __builtin_amdgcn_mfma_f32_16x16x32_bf16(af, bf2[n], accO[m][n], 0, 0, 0);
      }
    }
  }

  // ---- epilogue ----
  #pragma unroll
  for (int n = 0; n < NT2; ++n) {
    const int col = wid * (NOUT / 4) + n * 16 + l15;
    const float b2 = B2[col] * (float)(1 + DUAL);
    #pragma unroll
    for (int m = 0; m < 4; ++m)
      #pragma unroll
      for (int r = 0; r < 4; ++r) {
        const int gr = rowBase + m * 16 + lg * 4 + r;
        const float y = accO[m][n][r] + b2;
        if constexpr (OUT_BF16) Yb[(size_t)gr * NOUT + col] = f2bf(y);
        else                    Yf[(size_t)gr * NOUT + col] = y;
      }
  }
}

// ---------------------------------------------------------------------------
// Pair-local message + aggregation: one block per pair (432 edges, 216 nodes).
// DIR 0: msg([h_f,h_t,comb]) scattered by to_idx -> aggF
// DIR 1: msg([h_t,h_f,comb]) scattered by from_idx -> aggB
// Aggregate lives entirely in LDS (f32, ds atomics); flushed with plain stores.
// ---------------------------------------------------------------------------
template<int DIR>
__global__ __launch_bounds__(256)
void msgagg_pair(const float* __restrict__ H, const u16* __restrict__ CB,
                 const int* __restrict__ FI, const int* __restrict__ TI,
                 const u16* __restrict__ W1t, const float* __restrict__ B1,
                 const u16* __restrict__ W2t, const float* __restrict__ B2,
                 float* __restrict__ Agg)
{
  __shared__ float sAgg[NPG * 128];     // 110592 B
  __shared__ u16   sA[48 * 256];        // 24576 B
  __shared__ u16   sH[48 * 136];        // 13056 B (half-hidden, padded)

  const int tid = threadIdx.x;
  const int pair = blockIdx.x;
  const int edge0 = pair * EPG, node0 = pair * NPG;
  const int* A1 = DIR ? TI : FI;
  const int* A2 = DIR ? FI : TI;   // also the scatter index

  for (int i = tid; i < NPG * 128; i += 256) sAgg[i] = 0.f;
  __syncthreads();

  const int wid = tid >> 6, lane = tid & 63;
  const int l15 = lane & 15, lg = lane >> 4;

  for (int it = 0; it < 9; ++it) {
    const int rbase = it * 48;
    // stage A 48x256 (swizzled)
    for (int ch = tid; ch < 48 * 32; ch += 256) {
      const int r = ch >> 5, kc = ch & 31;
      const int er = edge0 + rbase + r, k0 = kc * 8;
      short8 pk;
      if (k0 < 64)       pk = cvt8(&H[(size_t)A1[er] * 64 + k0]);
      else if (k0 < 128) pk = cvt8(&H[(size_t)A2[er] * 64 + (k0 - 64)]);
      else               pk = *(const short8*)&CB[(size_t)er * 128 + (k0 - 128)];
      const int byte = ((r * 256 + k0) * 2) ^ ((r & 7) << 4);
      *(short8*)((char*)sA + byte) = pk;
    }
    __syncthreads();

    floatx4 acc2[3][2];
    #pragma unroll
    for (int m = 0; m < 3; ++m) { acc2[m][0] = floatx4{0,0,0,0}; acc2[m][1] = floatx4{0,0,0,0}; }

    #pragma unroll
    for (int half = 0; half < 2; ++half) {
      // layer1 for 128 hidden cols (2 n-tiles per wave)
      floatx4 acc1[3][2];
      #pragma unroll
      for (int m = 0; m < 3; ++m) { acc1[m][0] = floatx4{0,0,0,0}; acc1[m][1] = floatx4{0,0,0,0}; }
      for (int kk = 0; kk < 8; ++kk) {
        short8 bf[2];
        #pragma unroll
        for (int n = 0; n < 2; ++n) {
          const int col = half * 128 + wid * 32 + n * 16 + l15;
          bf[n] = *(const short8*)&W1t[(size_t)col * 256 + kk * 32 + lg * 8];
        }
        #pragma unroll
        for (int m = 0; m < 3; ++m) {
          const int r = m * 16 + l15;
          const int byte = ((r * 256 + kk * 32 + lg * 8) * 2) ^ ((r & 7) << 4);
          const short8 af = *(const short8*)((char*)sA + byte);
          acc1[m][0] = __builtin_amdgcn_mfma_f32_16x16x32_bf16(af, bf[0], acc1[m][0], 0, 0, 0);
          acc1[m][1] = __builtin_amdgcn_mfma_f32_16x16x32_bf16(af, bf[1], acc1[m][1], 0, 0, 0);
        }
      }
      __syncthreads();   // previous half's layer2 readers done
      #pragma unroll
      for (int n = 0; n < 2; ++n) {
        const int colL = wid * 32 + n * 16 + l15;
        const float b1 = B1[half * 128 + colL];
        #pragma unroll
        for (int m = 0; m < 3; ++m)
          #pragma unroll
          for (int r = 0; r < 4; ++r) {
            const int row = m * 16 + lg * 4 + r;
            float y = acc1[m][n][r] + b1;
            sH[row * 136 + colL] = f2bf(y > 0.f ? y : 0.f);
          }
      }
      __syncthreads();
      // layer2 partial (k over this half's 128 hidden dims)
      for (int kk = 0; kk < 4; ++kk) {
        short8 bf2[2];
        #pragma unroll
        for (int n = 0; n < 2; ++n) {
          const int col = wid * 32 + n * 16 + l15;
          bf2[n] = *(const short8*)&W2t[(size_t)col * 256 + half * 128 + kk * 32 + lg * 8];
        }
        #pragma unroll
        for (int m = 0; m < 3; ++m) {
          const short8 af = *(const short8*)&sH[(m * 16 + l15) * 136 + kk * 32 + lg * 8];
          acc2[m][0] = __builtin_amdgcn_mfma_f32_16x16x32_bf16(af, bf2[0], acc2[m][0], 0, 0, 0);
          acc2[m][1] = __builtin_amdgcn_mfma_f32_16x16x32_bf16(af, bf2[1], acc2[m][1], 0, 0, 0);
        }
      }
    }
    // scatter messages into LDS aggregate
    #pragma unroll
    for (int n = 0; n < 2; ++n) {
      const int col = wid * 32 + n * 16 + l15;
      const float b2 = B2[col];
      #pragma unroll
      for (int m = 0; m < 3; ++m)
        #pragma unroll
        for (int r = 0; r < 4; ++r) {
          const int er = edge0 + rbase + m * 16 + lg * 4 + r;
          const int node = A2[er] - node0;
          atomicAdd(&sAgg[node * 128 + col], acc2[m][n][r] + b2);
        }
    }
  }
  __syncthreads();
  for (int i = tid; i < NPG * 128; i += 256)
    Agg[(size_t)node0 * 128 + i] = sAgg[i];
}

// ---------------------------------------------------------------------------
// f32 fused MLP (kept for encoders + sinkhorn feature MLPs)
// IN_MODE: 0 plain X  5 q-side rows of e (zero-padded)  6 c-side rows of e
// SINGLE: 1 -> single layer
// ---------------------------------------------------------------------------
template<int K1, int HID, int NOUT, int IN_MODE, int SINGLE>
__global__ __launch_bounds__(256)
void fused_mlp(const float* __restrict__ X, const float* __restrict__ P1,
               const float* __restrict__ W1, const float* __restrict__ B1,
               const float* __restrict__ W2, const float* __restrict__ B2,
               float* __restrict__ Y, int maskLen)
{
  constexpr int RT = 32, BK = 32;
  constexpr int J1 = HID / 32;
  constexpr int J2 = NOUT / 32;
  constexpr int BMAX = (HID > NOUT ? HID : NOUT);
  __shared__ float sA[RT * 33];
  __shared__ float sB[BK * BMAX];
  __shared__ float sH[SINGLE ? 1 : RT * (HID + 1)];

  const int t  = threadIdx.x;
  const int tx = t & 31, ty = t >> 5;
  const int rowBase = blockIdx.x * RT;

  float acc[4][J1];
  #pragma unroll
  for (int i = 0; i < 4; ++i)
    #pragma unroll
    for (int j = 0; j < J1; ++j) acc[i][j] = 0.f;

  for (int kb = 0; kb < K1; kb += BK) {
    for (int l = t; l < RT * BK; l += 256) {
      const int r = l >> 5, k = l & 31;
      const int gr = rowBase + r, gk = kb + k;
      float v;
      if constexpr (IN_MODE == 0) {
        v = X[(size_t)gr * K1 + gk];
      } else {
        const int bb = gr >> 8, m = gr & 255;
        constexpr int off = (IN_MODE == 5) ? 0 : EQ_;
        constexpr int len = (IN_MODE == 5) ? EQ_ : EC_;
        v = (m < len) ? P1[((size_t)bb * EPG + off + m) * 128 + gk] : 0.f;
      }
      sA[r * 33 + k] = v;
    }
    for (int l = t * 4; l < BK * HID; l += 1024) {
      *(float4*)&sB[l] = *(const float4*)&W1[(size_t)(kb + l / HID) * HID + (l % HID)];
    }
    __syncthreads();
    #pragma unroll
    for (int k = 0; k < BK; ++k) {
      const float a0 = sA[(ty*4+0)*33+k], a1 = sA[(ty*4+1)*33+k],
                  a2 = sA[(ty*4+2)*33+k], a3 = sA[(ty*4+3)*33+k];
      #pragma unroll
      for (int j = 0; j < J1; ++j) {
        const float bb = sB[k * HID + tx + 32*j];
        acc[0][j] += a0 * bb; acc[1][j] += a1 * bb;
        acc[2][j] += a2 * bb; acc[3][j] += a3 * bb;
      }
    }
    __syncthreads();
  }

  if constexpr (SINGLE) {
    #pragma unroll
    for (int j = 0; j < J1; ++j) {
      const int col = tx + 32*j;
      const float bias = B1[col];
      #pragma unroll
      for (int i = 0; i < 4; ++i) {
        const int gr = rowBase + ty*4 + i;
        Y[(size_t)gr * HID + col] = acc[i][j] + bias;
      }
    }
  } else {
    #pragma unroll
    for (int j = 0; j < J1; ++j) {
      const int col = tx + 32*j;
      const float bias = B1[col];
      #pragma unroll
      for (int i = 0; i < 4; ++i) {
        float y = acc[i][j] + bias;
        sH[(ty*4+i) * (HID+1) + col] = y > 0.f ? y : 0.f;
      }
    }
    __syncthreads();

    float acc2[4][J2];
    #pragma unroll
    for (int i = 0; i < 4; ++i)
      #pragma unroll
      for (int j = 0; j < J2; ++j) acc2[i][j] = 0.f;

    for (int kb = 0; kb < HID; kb += BK) {
      for (int l = t * 4; l < BK * NOUT; l += 1024) {
        *(float4*)&sB[l] = *(const float4*)&W2[(size_t)(kb + l / NOUT) * NOUT + (l % NOUT)];
      }
      __syncthreads();
      #pragma unroll
      for (int k = 0; k < BK; ++k) {
        const float a0 = sH[(ty*4+0)*(HID+1) + kb + k],
                    a1 = sH[(ty*4+1)*(HID+1) + kb + k],
                    a2 = sH[(ty*4+2)*(HID+1) + kb + k],
                    a3 = sH[(ty*4+3)*(HID+1) + kb + k];
        #pragma unroll
        for (int j = 0; j < J2; ++j) {
          const float bb = sB[k * NOUT + tx + 32*j];
          acc2[0][j] += a0 * bb; acc2[1][j] += a1 * bb;
          acc2[2][j] += a2 * bb; acc2[3][j] += a3 * bb;
        }
      }
      __syncthreads();
    }
    #pragma unroll
    for (int j = 0; j < J2; ++j) {
      const int col = tx + 32*j;
      const float bias = B2[col];
      #pragma unroll
      for (int i = 0; i < 4; ++i) {
        const int gr = rowBase + ty*4 + i;
        float y = acc2[i][j] + bias;
        if (maskLen >= 0 && (gr & 255) >= maskLen) y = 0.f;
        Y[(size_t)gr * NOUT + col] = y;
      }
    }
  }
}

// ---------------------------------------------------------------------------
// S[b] = scale * fq[b] @ fc[b]^T
// ---------------------------------------------------------------------------
__global__ __launch_bounds__(256)
void gemm_nt_scale(const float* __restrict__ A, const float* __restrict__ Bm,
                   float* __restrict__ C, float scale)
{
  const int b = blockIdx.z, qt = blockIdx.x, ct = blockIdx.y;
  __shared__ float sA[64 * 68];
  __shared__ float sB[64 * 68];
  const int t = threadIdx.x;
  const int tx = t & 15, ty = t >> 4;
  const float* Ab = A  + (size_t)b * 16384 + (size_t)qt * 4096;
  const float* Bb = Bm + (size_t)b * 16384 + (size_t)ct * 4096;
  for (int l = t * 4; l < 64 * 64; l += 1024) {
    const int r = l >> 6, d = l & 63;
    *(float4*)&sA[r*68 + d] = *(const float4*)&Ab[r*64 + d];
    *(float4*)&sB[r*68 + d] = *(const float4*)&Bb[r*64 + d];
  }
  __syncthreads();
  float acc[4][4] = {};
  #pragma unroll
  for (int d = 0; d < 64; ++d) {
    float a[4], bb[4];
    #pragma unroll
    for (int i = 0; i < 4; ++i) a[i]  = sA[(ty*4+i)*68 + d];
    #pragma unroll
    for (int j = 0; j < 4; ++j) bb[j] = sB[(tx+16*j)*68 + d];
    #pragma unroll
    for (int i = 0; i < 4; ++i)
      #pragma unroll
      for (int j = 0; j < 4; ++j) acc[i][j] += a[i] * bb[j];
  }
  float* Cb = C + (size_t)b * 65536 + (size_t)(qt*64) * 256 + ct*64;
  #pragma unroll
  for (int i = 0; i < 4; ++i)
    #pragma unroll
    for (int j = 0; j < 4; ++j)
      Cb[(ty*4+i)*256 + tx + 16*j] = acc[i][j] * scale;
}

// ---------------------------------------------------------------------------
// Y rows r<maskRows at ((b*RPB + YOFF + r)*128) = op(P[b]) @ V,
// V gathered from e rows (zero-padded).
// ---------------------------------------------------------------------------
template<int TRANSA>
__global__ __launch_bounds__(256)
void gemm_plan(const float* __restrict__ P, const float* __restrict__ E,
               float* __restrict__ Y, int RPB, int YOFF, int VOFF, int VLEN,
               int maskRows)
{
  const int b = blockIdx.y, rt = blockIdx.x;
  __shared__ float sA[64 * 33];
  __shared__ float sB[32 * 128];
  const int t = threadIdx.x;
  const int tx = t & 15, ty = t >> 4;
  const float* Pb = P + (size_t)b * 65536;
  float acc[4][8] = {};
  for (int kb = 0; kb < 256; kb += 32) {
    if constexpr (TRANSA == 0) {
      for (int l = t; l < 64 * 32; l += 256) {
        const int r = l >> 5, k = l & 31;
        sA[r*33 + k] = Pb[(size_t)(rt*64 + r) * 256 + kb + k];
      }
    } else {
      for (int l = t; l < 64 * 32; l += 256) {
        const int r = l & 63, k = l >> 6;
        sA[r*33 + k] = Pb[(size_t)(kb + k) * 256 + rt*64 + r];
      }
    }
    for (int l = t * 4; l < 32 * 128; l += 1024) {
      const int vr = kb + (l >> 7), d = l & 127;
      float4 val = {0.f, 0.f, 0.f, 0.f};
      if (vr < VLEN) val = *(const float4*)&E[((size_t)b * EPG + VOFF + vr) * 128 + d];
      *(float4*)&sB[l] = val;
    }
    __syncthreads();
    #pragma unroll
    for (int k = 0; k < 32; ++k) {
      float a[4], bb[8];
      #pragma unroll
      for (int i = 0; i < 4; ++i) a[i]  = sA[(ty*4+i)*33 + k];
      #pragma unroll
      for (int j = 0; j < 8; ++j) bb[j] = sB[k*128 + tx + 16*j];
      #pragma unroll
      for (int i = 0; i < 4; ++i)
        #pragma unroll
        for (int j = 0; j < 8; ++j) acc[i][j] += a[i] * bb[j];
    }
    __syncthreads();
  }
  #pragma unroll
  for (int i = 0; i < 4; ++i) {
    const int r = rt*64 + ty*4 + i;
    if (r >= maskRows) continue;
    float* yr = Y + ((size_t)b * RPB + YOFF + r) * 128;
    #pragma unroll
    for (int j = 0; j < 8; ++j) yr[tx + 16*j] = acc[i][j];
  }
}

// ---------------------------------------------------------------------------
// sinkhorn potential steps
// ---------------------------------------------------------------------------
__global__ __launch_bounds__(256)
void sink_rowstep(const float* __restrict__ S, const float* __restrict__ v,
                  float* __restrict__ u)
{
  const int row  = blockIdx.x * 4 + (threadIdx.x >> 6);
  const int lane = threadIdx.x & 63;
  const int b = row >> 8;
  const float* Sr = S + (size_t)row * 256;
  const float* vb = v + b * 256;
  float m = -1e30f, s = 0.f;
  #pragma unroll
  for (int j = 0; j < 4; ++j) {
    const int c = lane + 64 * j;
    lse_online(m, s, Sr[c] + vb[c]);
  }
  #pragma unroll
  for (int off = 32; off; off >>= 1) {
    const float om = __shfl_xor(m, off);
    const float os = __shfl_xor(s, off);
    lse_merge(m, s, om, os);
  }
  if (lane == 0) u[row] = -(m + __logf(s));
}

__global__ __launch_bounds__(256)
void sink_colstep(const float* __restrict__ S, const float* __restrict__ u,
                  float* __restrict__ v)
{
  const int b = blockIdx.y;
  const int c = blockIdx.x * 64 + (threadIdx.x & 63);
  const int rg = threadIdx.x >> 6;
  const float* Sb = S + ((size_t)b << 16);
  const float* ub = u + b * 256;
  float m = -1e30f, s = 0.f;
  for (int r = rg * 64; r < rg * 64 + 64; ++r)
    lse_online(m, s, Sb[(size_t)r * 256 + c] + ub[r]);
  __shared__ float sm[256], ss[256];
  sm[threadIdx.x] = m; ss[threadIdx.x] = s;
  __syncthreads();
  if (rg == 0) {
    #pragma unroll
    for (int k = 1; k < 4; ++k)
      lse_merge(m, s, sm[threadIdx.x + 64*k], ss[threadIdx.x + 64*k]);
    v[b * 256 + c] = -(m + __logf(s));
  }
}

__global__ __launch_bounds__(256)
void planify(float* __restrict__ S, const float* __restrict__ u,
             const float* __restrict__ v)
{
  const int i = blockIdx.x * 256 + threadIdx.x;
  const int row = i >> 6;
  const int c4 = (i & 63) * 4;
  const int b = row >> 8;
  const float uu = u[row];
  const float* vb = v + b * 256;
  float4 sv = *(float4*)&S[(size_t)row * 256 + c4];
  sv.x = __expf(sv.x + uu + vb[c4+0]);
  sv.y = __expf(sv.y + uu + vb[c4+1]);
  sv.z = __expf(sv.z + uu + vb[c4+2]);
  sv.w = __expf(sv.w + uu + vb[c4+3]);
  *(float4*)&S[(size_t)row * 256 + c4] = sv;
}

// ---------------------------------------------------------------------------
// score[b] = -sum_{m<256,d} | (m<EQ ? e_q[m,d] : 0) - pc[m,d] |
// ---------------------------------------------------------------------------
__global__ __launch_bounds__(256)
void escore_kernel(const float* __restrict__ e, const float* __restrict__ pc,
                   float* __restrict__ out)
{
  const int b = blockIdx.x, t = threadIdx.x;
  float acc = 0.f;
  for (int i4 = t; i4 < 8192; i4 += 256) {
    const int flat = i4 * 4;
    const int m = flat >> 7, d = flat & 127;
    float4 p = *(const float4*)&pc[((size_t)b * 256 + m) * 128 + d];
    float4 q = {0.f, 0.f, 0.f, 0.f};
    if (m < EQ_) q = *(const float4*)&e[((size_t)b * EPG + m) * 128 + d];
    acc += fabsf(q.x - p.x) + fabsf(q.y - p.y) + fabsf(q.z - p.z) + fabsf(q.w - p.w);
  }
  __shared__ float red[256];
  red[t] = acc; __syncthreads();
  for (int s2 = 128; s2 > 0; s2 >>= 1) { if (t < s2) red[t] += red[t + s2]; __syncthreads(); }
  if (t == 0) out[b] = -red[0];
}

// ---------------------------------------------------------------------------
extern "C" void kernel_launch(void* const* d_in, const int* in_sizes, int n_in,
                              void* d_out, int out_size, void* d_ws, size_t ws_size,
                              hipStream_t stream)
{
  const float* node_features = (const float*)d_in[0];
  const float* edge_features = (const float*)d_in[1];
  const int*   from_idx      = (const int*)d_in[2];
  const int*   to_idx        = (const int*)d_in[3];
  const float* enc_node_W = (const float*)d_in[4];
  const float* enc_node_b = (const float*)d_in[5];
  const float* enc_edge_W = (const float*)d_in[6];
  const float* enc_edge_b = (const float*)d_in[7];
  const float* msg_W1 = (const float*)d_in[8];
  const float* msg_b1 = (const float*)d_in[9];
  const float* msg_W2 = (const float*)d_in[10];
  const float* msg_b2 = (const float*)d_in[11];
  const float* upd_W1 = (const float*)d_in[12];
  const float* upd_b1 = (const float*)d_in[13];
  const float* upd_W2 = (const float*)d_in[14];
  const float* upd_b2 = (const float*)d_in[15];
  const float* int_W1 = (const float*)d_in[16];
  const float* int_b1 = (const float*)d_in[17];
  const float* int_W2 = (const float*)d_in[18];
  const float* int_b2 = (const float*)d_in[19];
  const float* sink_W1 = (const float*)d_in[20];
  const float* sink_b1 = (const float*)d_in[21];
  const float* sink_W2 = (const float*)d_in[22];
  const float* sink_b2 = (const float*)d_in[23];
  float* out = (float*)d_out;

  float* wsf = (float*)d_ws;
  float* h   = wsf;                               // NN*64 f32
  float* e   = h + (size_t)NN * 64;               // NE*128 f32
  float* shr = e + (size_t)NE * 128;              // NE*128 f32 (inter | aggF+aggB | fq+fc | pc)
  float* S   = shr + (size_t)NE * 128;            // BATCH*65536 f32
  float* u   = S + (size_t)BATCH * 65536;
  float* v   = u + (size_t)BATCH * 256;
  u16* comb  = (u16*)(v + (size_t)BATCH * 256);   // NE*128 bf16
  u16* wi1 = comb + (size_t)NE * 128;             // 256x256
  u16* wi2 = wi1 + 65536;                         // 128x256
  u16* wm1 = wi2 + 32768;                         // 256x256
  u16* wm2 = wm1 + 65536;                         // 128x256
  u16* wu1 = wm2 + 32768;                         // 128x320
  u16* wu2 = wu1 + 40960;                         // 64x128

  float* aggF  = shr;
  float* aggB  = shr + (size_t)NN * 128;
  float* inter = shr;                             // EPG-row layout
  float* fq    = shr;
  float* fc    = shr + (size_t)BATCH * 16384;

  // weights -> bf16, transposed [N][K]
  wconv<<<256, 256, 0, stream>>>(int_W1, wi1, 256, 256);
  wconv<<<128, 256, 0, stream>>>(int_W2, wi2, 256, 128);
  wconv<<<256, 256, 0, stream>>>(msg_W1, wm1, 256, 256);
  wconv<<<128, 256, 0, stream>>>(msg_W2, wm2, 256, 128);
  wconv<<<160, 256, 0, stream>>>(upd_W1, wu1, 320, 128);
  wconv<<< 32, 256, 0, stream>>>(upd_W2, wu2, 128, 64);

  for (int ts = 0; ts < 2; ++ts) {
    // encoders (reset h, e)
    fused_mlp<32,64,64,0,1><<<NN/32, 256, 0, stream>>>(
        node_features, nullptr, enc_node_W, enc_node_b, nullptr, nullptr, h, -1);
    fused_mlp<32,128,128,0,1><<<NE/32, 256, 0, stream>>>(
        edge_features, nullptr, enc_edge_W, enc_edge_b, nullptr, nullptr, e, -1);

    for (int p = 0; p < 3; ++p) {
      // comb = MLP([e, inter])  (inter==0 for ts0 and ts1/p0)
      const float* interArg = (ts == 1 && p > 0) ? inter : nullptr;
      mlp_mfma<256,256,128,4,0,1><<<NE/64, 256, 0, stream>>>(
          e, interArg, nullptr, nullptr, nullptr, nullptr,
          wi1, int_b1, wi2, int_b2, nullptr, comb);
      // bidirectional messages + pair-local aggregation (no global atomics)
      msgagg_pair<0><<<BATCH, 256, 0, stream>>>(
          h, comb, from_idx, to_idx, wm1, msg_b1, wm2, msg_b2, aggF);
      msgagg_pair<1><<<BATCH, 256, 0, stream>>>(
          h, comb, from_idx, to_idx, wm1, msg_b1, wm2, msg_b2, aggB);
      // node update (in place)
      mlp_mfma<320,128,64,3,0,0><<<NN/64, 256, 0, stream>>>(
          h, aggF, aggB, nullptr, nullptr, nullptr,
          wu1, upd_b1, wu2, upd_b2, h, nullptr);
      // e = mf2 + mb2 with updated h (dual-direction fused)
      mlp_mfma<256,256,128,1,1,0><<<NE/64, 256, 0, stream>>>(
          h, nullptr, nullptr, comb, from_idx, to_idx,
          wm1, msg_b1, wm2, msg_b2, e, nullptr);
      // interaction features from last time step's transport plan
      if (ts == 1 && p < 2) {
        gemm_plan<0><<<dim3(4, BATCH), 256, 0, stream>>>(
            S, e, inter, EPG, 0,   EQ_, EC_, EQ_);
        gemm_plan<1><<<dim3(4, BATCH), 256, 0, stream>>>(
            S, e, inter, EPG, EQ_, 0,   EQ_, EC_);
      }
    }
    // sinkhorn features + plan
    fused_mlp<128,64,64,5,0><<<BATCH*8, 256, 0, stream>>>(
        nullptr, e, sink_W1, sink_b1, sink_W2, sink_b2, fq, EQ_);
    fused_mlp<128,64,64,6,0><<<BATCH*8, 256, 0, stream>>>(
        nullptr, e, sink_W1, sink_b1, sink_W2, sink_b2, fc, EC_);
    gemm_nt_scale<<<dim3(4,4,BATCH), 256, 0, stream>>>(fq, fc, S, 10.0f);
    hipMemsetAsync(v, 0, (size_t)BATCH * 256 * 4, stream);
    for (int it = 0; it < 10; ++it) {
      sink_rowstep<<<BATCH*64, 256, 0, stream>>>(S, v, u);
      sink_colstep<<<dim3(4, BATCH), 256, 0, stream>>>(S, u, v);
    }
    planify<<<BATCH*64, 256, 0, stream>>>(S, u, v);   // S := plan
  }

  // final score
  gemm_plan<0><<<dim3(4, BATCH), 256, 0, stream>>>(S, e, shr, 256, 0, EQ_, EC_, 256);
  escore_kernel<<<BATCH, 256, 0, stream>>>(e, shr, out);
}